// Round 8
// baseline (655737.061 us; speedup 1.0000x reference)
//
#include <hip/hip_runtime.h>
#include <hip/hip_bf16.h>

// ---------------------------------------------------------------------------
// FULL FLOAT64 pipeline (rounds 4/5: state + activations must be f64 —
// fp32-level noise flips borderline binarizations -> 0.05-scale errors).
// Round-8: round-7 counters showed (a) register spills from the prefetch
// (conv2 WRITE 71->441 MB = scratch writebacks) and (b) LDS-pipe-bound
// inner loop (per k: 96 LDS-cyc vs 64 VALU-cyc per wave). Fixes:
//   - W staging via __builtin_amdgcn_global_load_lds width=16 (row = 128
//     doubles = 64 lanes x 16 B, wave-uniform base) -> no wreg, no ds_writes
//   - A staging keeps a tiny areg prefetch (8 VGPRs)
//   - double-buffered LDS (A+W), ONE barrier per chunk, prefetch overlapped
// Summation order (tap -> cc -> k) unchanged -> bit-identical numerics.
//
//   job j = img * NSTRIP + s ; img = j >> ns_shift ; r0 = (j & (NSTRIP-1))*R
//   h0 slot: [(R+8) rows][256][8] f64 ; h1: [(R+4)][256][256] ;
//   h2: [(R+2)][256][256] ; h3 = h1 alias
//   packed weights f64: Wp[k*256+oc], k = tap*CIN+cin (tap-major)
//   xpA/xpB: [NPIX] f64 ping-pong state; d_out: [NPIX] f32
// ---------------------------------------------------------------------------

#define NPIX (4 * 256 * 256)

__device__ __forceinline__ void async_copy16(const double* g, double* lds) {
    __builtin_amdgcn_global_load_lds(
        (const __attribute__((address_space(1))) void*)g,
        (__attribute__((address_space(3))) void*)lds, 16, 0, 0);
}

// ---------------------- x (f32) -> xp (f64) init ---------------------------
__global__ __launch_bounds__(256) void xinit_kernel(
    const float* __restrict__ x, double* __restrict__ xp64)
{
    int p = blockIdx.x * 256 + threadIdx.x;
    xp64[p] = (double)x[p];
}

// ------------------- stencil features, job-sliced --------------------------
// grid (R+8, G); blockIdx.y = slot; job = job0 + slot.
__global__ __launch_bounds__(256) void stencil_strip(
    const float* __restrict__ x, const double* __restrict__ xp,
    double* __restrict__ h0, size_t h0_is,
    int job0, int ns_shift, int R)
{
    int slot = blockIdx.y;
    int j = job0 + slot;
    int img = j >> ns_shift;
    int r0 = (j & ((1 << ns_shift) - 1)) * R;
    int pbase = img << 16;
    int y = (r0 - 4 + blockIdx.x) & 255;
    int col = threadIdx.x;
    double q[8];
    int s = 0, idx = 0;
    #pragma unroll
    for (int i = -1; i <= 1; ++i)
        #pragma unroll
        for (int jj = -1; jj <= 1; ++jj) {
            if (i == 0 && jj == 0) continue;
            int ys = (y - i) & 255, xs = (col - jj) & 255;
            double v = xp[pbase + ((ys << 8) | xs)];
            q[idx++] = v;
            s += (v > 0.5) ? 1 : 0;
        }
    double c = xp[pbase + ((y << 8) | col)];
    bool alive = c > 0.5;
    bool binnext = (s == 3) || (alive && s == 2);
    double c0 = 1.0, c1 = 0.0, c2 = 0.0, c3 = 0.0;   // count DP, ref order
    #pragma unroll
    for (int k = 0; k < 8; ++k) {
        double qq = q[k], r = 1.0 - qq;
        c3 = c3 * r + c2 * qq;
        c2 = c2 * r + c1 * qq;
        c1 = c1 * r + c0 * qq;
        c0 = c0 * r;
    }
    double xpred = c3 + c2 * c;
    double* o = h0 + slot * h0_is + ((size_t)blockIdx.x * 256 + col) * 8;
    o[0] = (double)x[pbase + ((y << 8) | col)];
    o[1] = c;
    o[2] = alive ? 1.0 : 0.0;
    o[3] = xpred;
    o[4] = binnext ? 1.0 : 0.0;
    o[5] = 0.0; o[6] = 0.0; o[7] = 0.0;
}

// ------------------- f64 direct-conv GEMM (Cout=256) -----------------------
// Block tile: 128 px x 128 oc, 256 threads, 8x8/thread.
//   thread px = pm0 + tm*8 + i ; thread oc = on0 + tn + 16*j (conflict-free)
// Double-buffered LDS; W via async global->LDS; A via areg prefetch.
template<int CIN, int TK, int KH, int KW>
__global__ __launch_bounds__(256, 2) void conv_gemm(
    const double* __restrict__ A,    // [aRows, 256, CIN] per slot
    size_t a_is,
    const double* __restrict__ Wp,   // [KH*KW*CIN, 256]
    const float* __restrict__ bias,  // [256] f32
    double* __restrict__ O,          // [oRows, 256, 256] per slot
    size_t o_is,
    int delta)
{
    constexpr int PW = KW / 2, PH = KH / 2;
    constexpr int CHUNKS = CIN / TK;
    constexpr int NCH = KH * KW * CHUNKS;
    constexpr int LPP = TK / 2;               // lanes per pixel (A staging)
    constexpr int PPR = 256 / LPP;
    constexpr int ROUNDS = 128 / PPR;
    constexpr int WROWS = TK / 4;             // W rows per wave (4 waves)

    __shared__ double Asmem[2][TK][130];      // [buf][k][px] transposed
    __shared__ double Wsmem[2][TK][128];      // [buf][k][oc], rows = 1024 B

    const double* Ai = A + blockIdx.z * a_is;
    double* Oi = O + blockIdx.z * o_is;

    const int tid = threadIdx.x;
    const int pm0 = blockIdx.x * 128;
    const int on0 = blockIdx.y * 128;
    const int tn = tid & 15, tm = tid >> 4;
    const int part = tid % LPP;
    const int pixA = tid / LPP;
    const int wave = tid >> 6, lane = tid & 63;

    double2 areg[ROUNDS];

    auto prefA = [&](int ch) {
        int tap = ch / CHUNKS, cc = ch % CHUNKS;
        int dy = tap / KW - PH, dx = tap % KW - PW;
        int c0 = cc * TK;
        #pragma unroll
        for (int r = 0; r < ROUNDS; ++r) {
            int pix = r * PPR + pixA;
            int pl = pm0 + pix;
            int yl = pl >> 8, col = pl & 255;
            int xs = (col + dx) & 255;
            int srcpx = ((yl + dy + delta) << 8) | xs;
            areg[r] = *(const double2*)(Ai + (size_t)srcpx * CIN + c0 + part * 2);
        }
    };
    auto issueW = [&](int ch, int buf) {
        int tap = ch / CHUNKS, cc = ch % CHUNKS;
        int kglob = tap * CIN + cc * TK;
        #pragma unroll
        for (int r = 0; r < WROWS; ++r) {
            int row = wave * WROWS + r;
            async_copy16(&Wp[(size_t)(kglob + row) * 256 + on0 + lane * 2],
                         &Wsmem[buf][row][0]);
        }
    };
    auto storeA = [&](int buf) {
        #pragma unroll
        for (int r = 0; r < ROUNDS; ++r) {
            int pix = r * PPR + pixA;
            Asmem[buf][part * 2 + 0][pix] = areg[r].x;
            Asmem[buf][part * 2 + 1][pix] = areg[r].y;
        }
    };

    double acc[8][8] = {};
    prefA(0);
    issueW(0, 0);
    storeA(0);

    #pragma unroll 1
    for (int ch = 0; ch < NCH; ++ch) {
        const int cur = ch & 1, nxt = cur ^ 1;
        __syncthreads();            // buf[cur]: A visible, async W drained
        if (ch + 1 < NCH) {
            issueW(ch + 1, nxt);    // overlaps compute below
            prefA(ch + 1);
        }
        #pragma unroll
        for (int k = 0; k < TK; ++k) {
            double av[8], bv[8];
            #pragma unroll
            for (int i = 0; i < 8; ++i) av[i] = Asmem[cur][k][tm * 8 + i];
            #pragma unroll
            for (int j = 0; j < 8; ++j) bv[j] = Wsmem[cur][k][tn + 16 * j];
            #pragma unroll
            for (int i = 0; i < 8; ++i)
                #pragma unroll
                for (int j = 0; j < 8; ++j)
                    acc[i][j] = fma(av[i], bv[j], acc[i][j]);
        }
        if (ch + 1 < NCH) storeA(nxt);   // other buffer; next barrier publishes
    }

    double bb[8];
    #pragma unroll
    for (int j = 0; j < 8; ++j) bb[j] = (double)bias[on0 + tn + 16 * j];
    #pragma unroll
    for (int i = 0; i < 8; ++i) {
        int pl = pm0 + tm * 8 + i;
        double* dst = Oi + (size_t)pl * 256 + on0;
        #pragma unroll
        for (int j = 0; j < 8; ++j)
            dst[tn + 16 * j] = fmax(acc[i][j] + bb[j], 0.0);
    }
}

// --------------- conv4: 256->1, 3x3, + sigmoid, wave-per-pixel -------------
// grid (R*4, G); blockIdx.y = slot; job = job0 + slot.
__global__ __launch_bounds__(256) void conv4_sig(
    const double* __restrict__ H3, size_t h3_is,
    const float* __restrict__ w4, const float* __restrict__ b4,
    float* __restrict__ out, double* __restrict__ xp_new,
    int job0, int ns_shift, int R)
{
    __shared__ double w4s[2304];     // w4[cin][kh][kw] f64
    int tid = threadIdx.x;
    for (int i = tid; i < 2304; i += 256) w4s[i] = (double)w4[i];
    __syncthreads();
    int slot = blockIdx.y;
    int j = job0 + slot;
    int img = j >> ns_shift;
    int r0 = (j & ((1 << ns_shift) - 1)) * R;
    const double* H3i = H3 + slot * h3_is;
    int pbase = img << 16;
    int lane = tid & 63, wv = tid >> 6;
    int p0 = blockIdx.x * 64 + wv * 16;
    for (int pi = 0; pi < 16; ++pi) {
        int pl = p0 + pi;
        int yl = pl >> 8, col = pl & 255;
        double acc = 0.0;
        #pragma unroll
        for (int tap = 0; tap < 9; ++tap) {
            int row = yl + tap / 3 - 1 + 1;                 // delta = 1
            int xs = (col + tap % 3 - 1) & 255;
            const double* src = H3i + (size_t)((row << 8) | xs) * 256;
            #pragma unroll
            for (int jj = 0; jj < 4; ++jj) {
                int c = lane + 64 * jj;
                acc = fma(src[c], w4s[c * 9 + tap], acc);
            }
        }
        #pragma unroll
        for (int off = 32; off; off >>= 1) acc += __shfl_xor(acc, off, 64);
        if (lane == 0) {
            double v = acc + (double)b4[0];
            double s = 1.0 / (1.0 + exp(-v));
            int p = pbase + (((r0 + yl) << 8) | col);
            out[p] = (float)s;
            xp_new[p] = s;
        }
    }
}

// ----------------------------- weight repacks (f32 -> f64) -----------------
__global__ void repack_w1(const float* __restrict__ w1, double* __restrict__ W1p) {
    int t = blockIdx.x * 256 + threadIdx.x;           // [(tap*8+cin)*256+oc]
    if (t >= 25 * 8 * 256) return;
    int oc = t & 255, cin = (t >> 8) & 7, tap = t >> 11;
    W1p[t] = (cin < 5) ? (double)w1[oc * 125 + cin * 25 + tap] : 0.0;
}
__global__ void repack_w2(const float* __restrict__ w2, double* __restrict__ W2p) {
    int t = blockIdx.x * 256 + threadIdx.x;           // [(tap*256+cin)*256+oc]
    if (t >= 9 * 256 * 256) return;
    int oc = t & 255, cin = (t >> 8) & 255, tap = t >> 16;
    W2p[t] = (double)w2[((oc << 8) | cin) * 9 + tap];
}
__global__ void repack_w3(const float* __restrict__ w3, double* __restrict__ W3p) {
    int t = blockIdx.x * 256 + threadIdx.x;           // [cin*256+oc]
    if (t >= 256 * 256) return;
    int oc = t & 255, cin = t >> 8;
    W3p[t] = (double)w3[oc * 256 + cin];
}

// ------------------------------- launcher ----------------------------------
extern "C" void kernel_launch(void* const* d_in, const int* in_sizes, int n_in,
                              void* d_out, int out_size, void* d_ws, size_t ws_size,
                              hipStream_t stream)
{
    const float* x  = (const float*)d_in[0];
    const float* w1 = (const float*)d_in[1];
    const float* b1 = (const float*)d_in[2];
    const float* w2 = (const float*)d_in[3];
    const float* b2 = (const float*)d_in[4];
    const float* w3 = (const float*)d_in[5];
    const float* b3 = (const float*)d_in[6];
    const float* w4 = (const float*)d_in[7];
    const float* b4 = (const float*)d_in[8];
    float* out = (float*)d_out;                      // f32 output

    char* ws = (char*)d_ws;
    double* W1p = (double*)(ws);                     //   409,600 B
    double* W2p = (double*)(ws + 409600ull);         // 4,718,592 B
    double* W3p = (double*)(ws + 5128192ull);        //   524,288 B
    double* xpA = (double*)(ws + 5652480ull);        // 2,097,152 B
    double* xpB = (double*)(ws + 7749632ull);        // 2,097,152 B
    char*  bufs = ws + 9846784ull;
    const size_t base_need = 9846784ull;
    const size_t ROWD  = 524288ull;                  // 256*256 f64 row bytes
    const size_t ROWH0 = 16384ull;                   // 256*8 f64 row bytes

    // (R, G) tier ladder: maximize per-launch blocks under ws_size.
    // conv2 grid = ((R+2)*2, 2, G) -> G*(R+2)*4 blocks (tier visible there).
    const int cand_r[15] = {32, 32, 16, 32, 16, 8, 16, 8, 4, 8, 16, 4, 8, 4, 2};
    const int cand_g[15] = { 4,  3,  4,  2,  3, 4,  2, 3, 4, 2,  1, 2, 1, 1, 1};
    int R = 2, G = 1;
    for (int ci = 0; ci < 15; ++ci) {
        int r = cand_r[ci], g = cand_g[ci];
        size_t need = base_need + (size_t)g *
            ((size_t)(r + 8) * ROWH0 + (size_t)(2 * r + 6) * ROWD);
        if (ws_size >= need) { R = r; G = g; break; }
    }
    int ns_shift = (R == 32) ? 3 : (R == 16) ? 4 : (R == 8) ? 5 : (R == 4) ? 6 : 7;
    const int NSTRIP = 256 / R;
    const int jobs = 4 * NSTRIP;

    double* h0 = (double*)bufs;
    double* h1 = (double*)(bufs + (size_t)G * (R + 8) * ROWH0);
    double* h2 = (double*)((char*)h1 + (size_t)G * (R + 4) * ROWD);
    double* h3 = h1;                                 // alias, stride h1_is
    const size_t h0_is = (size_t)(R + 8) * 256 * 8;  // element strides
    const size_t h1_is = (size_t)(R + 4) * 256 * 256;
    const size_t h2_is = (size_t)(R + 2) * 256 * 256;

    repack_w1<<<200, 256, 0, stream>>>(w1, W1p);
    repack_w2<<<2304, 256, 0, stream>>>(w2, W2p);
    repack_w3<<<256, 256, 0, stream>>>(w3, W3p);
    xinit_kernel<<<NPIX / 256, 256, 0, stream>>>(x, xpA);

    for (int it = 0; it < 5; ++it) {                 // n_it = 5 (setup constant)
        const double* xp_rd = (it & 1) ? xpB : xpA;  // ping-pong: no intra-iter
        double*       xp_wr = (it & 1) ? xpA : xpB;  // RAW hazard (round 5 bug)
        for (int j0 = 0; j0 < jobs; j0 += G) {
            int g = (jobs - j0 < G) ? (jobs - j0) : G;
            stencil_strip<<<dim3(R + 8, g), 256, 0, stream>>>(
                x, xp_rd, h0, h0_is, j0, ns_shift, R);
            conv_gemm<8, 8, 5, 5><<<dim3((R + 4) * 2, 2, g), 256, 0, stream>>>(
                h0, h0_is, W1p, b1, h1, h1_is, 2);
            conv_gemm<256, 16, 3, 3><<<dim3((R + 2) * 2, 2, g), 256, 0, stream>>>(
                h1, h1_is, W2p, b2, h2, h2_is, 1);
            conv_gemm<256, 16, 1, 1><<<dim3((R + 2) * 2, 2, g), 256, 0, stream>>>(
                h2, h2_is, W3p, b3, h3, h1_is, 0);
            conv4_sig<<<dim3(R * 4, g), 256, 0, stream>>>(
                h3, h1_is, w4, b4, out, xp_wr, j0, ns_shift, R);
        }
    }
}

// Round 11
// 54147.913 us; speedup vs baseline: 12.1101x; 12.1101x over previous
//
#include <hip/hip_runtime.h>
#include <hip/hip_bf16.h>

// ---------------------------------------------------------------------------
// FULL FLOAT64 pipeline (rounds 4/5: state + activations must be f64).
// Round-11: round-10's MFMA GEMM validated at the 1.95e-3 floor on launch #1
// but diverged on all subsequent launches (graph replays + fresh tripwires,
// mutually consistent). Differential vs replay-proven rounds 6/7 isolates the
// novelty to the IN-KERNEL runtime layout probe. Fix: externalize the probe
// into a one-wave kernel that writes `mode` to ws once per launch; conv_gemm
// reads it as a uniform scalar. Hot loop/epilogue math unchanged (verified).
//
//   mode 0: row=4*lq+i, col=lr     mode 1: row=4*i+lq, col=lr
//   mode 2: row=lr, col=4*lq+i     mode 3: row=lr, col=4*i+lq
// (k-slot permutations are summed over -> harmless.)
//
//   job j = img * NSTRIP + s ; img = j >> ns_shift ; r0 = (j & (NSTRIP-1))*R
//   h0 slot: [(R+8) rows][256][8] f64 ; h1: [(R+4)][256][256] ;
//   h2: [(R+2)][256][256] ; h3 = h1 alias
//   packed weights f64: Wp[k*256+oc], k = tap*CIN+cin (tap-major)
//   xpA/xpB: [NPIX] f64 ping-pong state; d_out: [NPIX] f32
// ---------------------------------------------------------------------------

#define NPIX (4 * 256 * 256)

typedef double v4d __attribute__((ext_vector_type(4)));

// ---------------- one-wave f64-MFMA C/D-layout probe -----------------------
// probe1: A=lr-label, B=ones -> D[m][n] = 4*m ; probe2: A=ones, B=lr -> 4*n.
// lane16 (lq=1,lr=0) reg0 predictions: m0:16 m1:4 (v1) / m2:16 m3:4 (v2).
__global__ __launch_bounds__(64) void probe_mode(int* __restrict__ modep)
{
    int lr = threadIdx.x & 15;
    v4d p1 = {}, p2 = {};
    p1 = __builtin_amdgcn_mfma_f64_16x16x4f64((double)lr, 1.0, p1, 0, 0, 0);
    p2 = __builtin_amdgcn_mfma_f64_16x16x4f64(1.0, (double)lr, p2, 0, 0, 0);
    double v1 = __shfl(p1[0], 16);
    double v2 = __shfl(p2[0], 16);
    if (threadIdx.x == 0)
        *modep = (v1 == 16.0) ? 0 : (v1 == 4.0) ? 1 : (v2 == 16.0) ? 2 : 3;
}

// ---------------------- x (f32) -> xp (f64) init ---------------------------
__global__ __launch_bounds__(256) void xinit_kernel(
    const float* __restrict__ x, double* __restrict__ xp64)
{
    int p = blockIdx.x * 256 + threadIdx.x;
    xp64[p] = (double)x[p];
}

// ------------------- stencil features, job-sliced --------------------------
// grid (R+8, G); blockIdx.y = slot; job = job0 + slot.
__global__ __launch_bounds__(256) void stencil_strip(
    const float* __restrict__ x, const double* __restrict__ xp,
    double* __restrict__ h0, size_t h0_is,
    int job0, int ns_shift, int R)
{
    int slot = blockIdx.y;
    int j = job0 + slot;
    int img = j >> ns_shift;
    int r0 = (j & ((1 << ns_shift) - 1)) * R;
    int pbase = img << 16;
    int y = (r0 - 4 + blockIdx.x) & 255;
    int col = threadIdx.x;
    double q[8];
    int s = 0, idx = 0;
    #pragma unroll
    for (int i = -1; i <= 1; ++i)
        #pragma unroll
        for (int jj = -1; jj <= 1; ++jj) {
            if (i == 0 && jj == 0) continue;
            int ys = (y - i) & 255, xs = (col - jj) & 255;
            double v = xp[pbase + ((ys << 8) | xs)];
            q[idx++] = v;
            s += (v > 0.5) ? 1 : 0;
        }
    double c = xp[pbase + ((y << 8) | col)];
    bool alive = c > 0.5;
    bool binnext = (s == 3) || (alive && s == 2);
    double c0 = 1.0, c1 = 0.0, c2 = 0.0, c3 = 0.0;   // count DP, ref order
    #pragma unroll
    for (int k = 0; k < 8; ++k) {
        double qq = q[k], r = 1.0 - qq;
        c3 = c3 * r + c2 * qq;
        c2 = c2 * r + c1 * qq;
        c1 = c1 * r + c0 * qq;
        c0 = c0 * r;
    }
    double xpred = c3 + c2 * c;
    double* o = h0 + slot * h0_is + ((size_t)blockIdx.x * 256 + col) * 8;
    o[0] = (double)x[pbase + ((y << 8) | col)];
    o[1] = c;
    o[2] = alive ? 1.0 : 0.0;
    o[3] = xpred;
    o[4] = binnext ? 1.0 : 0.0;
    o[5] = 0.0; o[6] = 0.0; o[7] = 0.0;
}

// ------------------- f64 MFMA direct-conv GEMM (Cout=256) ------------------
// Block tile: 128 px x 128 oc, 256 threads = 4 waves.
// Wave (wr,wc) quadrant: px [wr, +64), oc [wc, +64) = 4x4 MFMA tiles.
// Staging identical to round 6 (proven spill-free). `mode` from ws (uniform).
template<int CIN, int TK, int KH, int KW>
__global__ __launch_bounds__(256, 2) void conv_gemm(
    const double* __restrict__ A,    // [aRows, 256, CIN] per slot
    size_t a_is,
    const double* __restrict__ Wp,   // [KH*KW*CIN, 256]
    const float* __restrict__ bias,  // [256] f32
    double* __restrict__ O,          // [oRows, 256, 256] per slot
    size_t o_is,
    int delta,
    const int* __restrict__ modep)
{
    constexpr int PW = KW / 2, PH = KH / 2;
    constexpr int CHUNKS = CIN / TK;
    __shared__ double Asmem[TK][130];   // [k][px] transposed
    __shared__ double Wsmem[TK][128];   // [k][oc]

    const double* Ai = A + blockIdx.z * a_is;
    double* Oi = O + blockIdx.z * o_is;
    const int mode = *modep;            // uniform s_load, probed this launch

    const int tid = threadIdx.x;
    const int pm0 = blockIdx.x * 128;
    const int on0 = blockIdx.y * 128;
    const int lane = tid & 63, wave = tid >> 6;
    const int lq = lane >> 4, lr = lane & 15;
    const int wr = (wave >> 1) * 64;          // wave px-quadrant base
    const int wc = (wave & 1) * 64;           // wave oc-quadrant base

    // staging mappings (round 6)
    constexpr int LPP = TK / 2;               // lanes per pixel
    constexpr int PPR = 256 / LPP;
    constexpr int ROUNDS = 128 / PPR;
    const int part = tid % LPP;
    const int pixA = tid / LPP;
    const int wrow = tid >> 6;
    const int wcol = (tid & 63) << 1;

    v4d acc[4][4] = {};

    for (int tap = 0; tap < KH * KW; ++tap) {
        const int dy = tap / KW - PH, dx = tap % KW - PW;
        for (int cc = 0; cc < CHUNKS; ++cc) {
            const int c0 = cc * TK;
            const int kglob = tap * CIN + c0;
            #pragma unroll
            for (int r = 0; r < TK / 4; ++r) {
                int row = r * 4 + wrow;
                *(double2*)&Wsmem[row][wcol] =
                    *(const double2*)&Wp[(size_t)(kglob + row) * 256 + on0 + wcol];
            }
            #pragma unroll
            for (int r = 0; r < ROUNDS; ++r) {
                int pix = r * PPR + pixA;
                int pl = pm0 + pix;
                int yl = pl >> 8, col = pl & 255;
                int xs = (col + dx) & 255;
                int srcpx = ((yl + dy + delta) << 8) | xs;
                const double2 v = *(const double2*)(
                    Ai + (size_t)srcpx * CIN + c0 + part * 2);
                Asmem[part * 2 + 0][pix] = v.x;
                Asmem[part * 2 + 1][pix] = v.y;
            }
            __syncthreads();
            #pragma unroll
            for (int k0 = 0; k0 < TK / 4; ++k0) {
                const int kk = k0 * 4 + lq;
                double a[4], b[4];
                #pragma unroll
                for (int rt = 0; rt < 4; ++rt)
                    a[rt] = Asmem[kk][wr + rt * 16 + lr];
                #pragma unroll
                for (int ct = 0; ct < 4; ++ct)
                    b[ct] = Wsmem[kk][wc + ct * 16 + lr];
                #pragma unroll
                for (int rt = 0; rt < 4; ++rt)
                    #pragma unroll
                    for (int ct = 0; ct < 4; ++ct)
                        acc[rt][ct] = __builtin_amdgcn_mfma_f64_16x16x4f64(
                            a[rt], b[ct], acc[rt][ct], 0, 0, 0);
            }
            __syncthreads();
        }
    }

    // epilogue: bias + relu; (row,col) per probed mode
    #pragma unroll
    for (int rt = 0; rt < 4; ++rt)
        #pragma unroll
        for (int ct = 0; ct < 4; ++ct)
            #pragma unroll
            for (int i = 0; i < 4; ++i) {
                int hq = lq * 4 + i, hi = i * 4 + lq;
                int rl = (mode == 0) ? hq : (mode == 1) ? hi : lr;
                int cl = (mode <= 1) ? lr : (mode == 2) ? hq : hi;
                int px = pm0 + wr + rt * 16 + rl;
                int oc = on0 + wc + ct * 16 + cl;
                Oi[(size_t)px * 256 + oc] =
                    fmax(acc[rt][ct][i] + (double)bias[oc], 0.0);
            }
}

// --------------- conv4: 256->1, 3x3, + sigmoid, wave-per-pixel -------------
// grid (R*4, G); blockIdx.y = slot; job = job0 + slot.
__global__ __launch_bounds__(256) void conv4_sig(
    const double* __restrict__ H3, size_t h3_is,
    const float* __restrict__ w4, const float* __restrict__ b4,
    float* __restrict__ out, double* __restrict__ xp_new,
    int job0, int ns_shift, int R)
{
    __shared__ double w4s[2304];     // w4[cin][kh][kw] f64
    int tid = threadIdx.x;
    for (int i = tid; i < 2304; i += 256) w4s[i] = (double)w4[i];
    __syncthreads();
    int slot = blockIdx.y;
    int j = job0 + slot;
    int img = j >> ns_shift;
    int r0 = (j & ((1 << ns_shift) - 1)) * R;
    const double* H3i = H3 + slot * h3_is;
    int pbase = img << 16;
    int lane = tid & 63, wv = tid >> 6;
    int p0 = blockIdx.x * 64 + wv * 16;
    for (int pi = 0; pi < 16; ++pi) {
        int pl = p0 + pi;
        int yl = pl >> 8, col = pl & 255;
        double acc = 0.0;
        #pragma unroll
        for (int tap = 0; tap < 9; ++tap) {
            int row = yl + tap / 3 - 1 + 1;                 // delta = 1
            int xs = (col + tap % 3 - 1) & 255;
            const double* src = H3i + (size_t)((row << 8) | xs) * 256;
            #pragma unroll
            for (int jj = 0; jj < 4; ++jj) {
                int c = lane + 64 * jj;
                acc = fma(src[c], w4s[c * 9 + tap], acc);
            }
        }
        #pragma unroll
        for (int off = 32; off; off >>= 1) acc += __shfl_xor(acc, off, 64);
        if (lane == 0) {
            double v = acc + (double)b4[0];
            double s = 1.0 / (1.0 + exp(-v));
            int p = pbase + (((r0 + yl) << 8) | col);
            out[p] = (float)s;
            xp_new[p] = s;
        }
    }
}

// ----------------------------- weight repacks (f32 -> f64) -----------------
__global__ void repack_w1(const float* __restrict__ w1, double* __restrict__ W1p) {
    int t = blockIdx.x * 256 + threadIdx.x;           // [(tap*8+cin)*256+oc]
    if (t >= 25 * 8 * 256) return;
    int oc = t & 255, cin = (t >> 8) & 7, tap = t >> 11;
    W1p[t] = (cin < 5) ? (double)w1[oc * 125 + cin * 25 + tap] : 0.0;
}
__global__ void repack_w2(const float* __restrict__ w2, double* __restrict__ W2p) {
    int t = blockIdx.x * 256 + threadIdx.x;           // [(tap*256+cin)*256+oc]
    if (t >= 9 * 256 * 256) return;
    int oc = t & 255, cin = (t >> 8) & 255, tap = t >> 16;
    W2p[t] = (double)w2[((oc << 8) | cin) * 9 + tap];
}
__global__ void repack_w3(const float* __restrict__ w3, double* __restrict__ W3p) {
    int t = blockIdx.x * 256 + threadIdx.x;           // [cin*256+oc]
    if (t >= 256 * 256) return;
    int oc = t & 255, cin = t >> 8;
    W3p[t] = (double)w3[oc * 256 + cin];
}

// ------------------------------- launcher ----------------------------------
extern "C" void kernel_launch(void* const* d_in, const int* in_sizes, int n_in,
                              void* d_out, int out_size, void* d_ws, size_t ws_size,
                              hipStream_t stream)
{
    const float* x  = (const float*)d_in[0];
    const float* w1 = (const float*)d_in[1];
    const float* b1 = (const float*)d_in[2];
    const float* w2 = (const float*)d_in[3];
    const float* b2 = (const float*)d_in[4];
    const float* w3 = (const float*)d_in[5];
    const float* b3 = (const float*)d_in[6];
    const float* w4 = (const float*)d_in[7];
    const float* b4 = (const float*)d_in[8];
    float* out = (float*)d_out;                      // f32 output

    char* ws = (char*)d_ws;
    double* W1p = (double*)(ws);                     //   409,600 B
    double* W2p = (double*)(ws + 409600ull);         // 4,718,592 B
    double* W3p = (double*)(ws + 5128192ull);        //   524,288 B
    double* xpA = (double*)(ws + 5652480ull);        // 2,097,152 B
    double* xpB = (double*)(ws + 7749632ull);        // 2,097,152 B
    int*   modep = (int*)(ws + 9846784ull);          //       256 B
    char*  bufs = ws + 9847040ull;
    const size_t base_need = 9847040ull;
    const size_t ROWD  = 524288ull;                  // 256*256 f64 row bytes
    const size_t ROWH0 = 16384ull;                   // 256*8 f64 row bytes

    // (R, G) tier ladder: maximize per-launch blocks under ws_size.
    // conv2 grid = ((R+2)*2, 2, G) -> G*(R+2)*4 blocks (tier visible there).
    const int cand_r[15] = {32, 32, 16, 32, 16, 8, 16, 8, 4, 8, 16, 4, 8, 4, 2};
    const int cand_g[15] = { 4,  3,  4,  2,  3, 4,  2, 3, 4, 2,  1, 2, 1, 1, 1};
    int R = 2, G = 1;
    for (int ci = 0; ci < 15; ++ci) {
        int r = cand_r[ci], g = cand_g[ci];
        size_t need = base_need + (size_t)g *
            ((size_t)(r + 8) * ROWH0 + (size_t)(2 * r + 6) * ROWD);
        if (ws_size >= need) { R = r; G = g; break; }
    }
    int ns_shift = (R == 32) ? 3 : (R == 16) ? 4 : (R == 8) ? 5 : (R == 4) ? 6 : 7;
    const int NSTRIP = 256 / R;
    const int jobs = 4 * NSTRIP;

    double* h0 = (double*)bufs;
    double* h1 = (double*)(bufs + (size_t)G * (R + 8) * ROWH0);
    double* h2 = (double*)((char*)h1 + (size_t)G * (R + 4) * ROWD);
    double* h3 = h1;                                 // alias, stride h1_is
    const size_t h0_is = (size_t)(R + 8) * 256 * 8;  // element strides
    const size_t h1_is = (size_t)(R + 4) * 256 * 256;
    const size_t h2_is = (size_t)(R + 2) * 256 * 256;

    probe_mode<<<1, 64, 0, stream>>>(modep);
    repack_w1<<<200, 256, 0, stream>>>(w1, W1p);
    repack_w2<<<2304, 256, 0, stream>>>(w2, W2p);
    repack_w3<<<256, 256, 0, stream>>>(w3, W3p);
    xinit_kernel<<<NPIX / 256, 256, 0, stream>>>(x, xpA);

    for (int it = 0; it < 5; ++it) {                 // n_it = 5 (setup constant)
        const double* xp_rd = (it & 1) ? xpB : xpA;  // ping-pong: no intra-iter
        double*       xp_wr = (it & 1) ? xpA : xpB;  // RAW hazard (round 5 bug)
        for (int j0 = 0; j0 < jobs; j0 += G) {
            int g = (jobs - j0 < G) ? (jobs - j0) : G;
            stencil_strip<<<dim3(R + 8, g), 256, 0, stream>>>(
                x, xp_rd, h0, h0_is, j0, ns_shift, R);
            conv_gemm<8, 8, 5, 5><<<dim3((R + 4) * 2, 2, g), 256, 0, stream>>>(
                h0, h0_is, W1p, b1, h1, h1_is, 2, modep);
            conv_gemm<256, 16, 3, 3><<<dim3((R + 2) * 2, 2, g), 256, 0, stream>>>(
                h1, h1_is, W2p, b2, h2, h2_is, 1, modep);
            conv_gemm<256, 16, 1, 1><<<dim3((R + 2) * 2, 2, g), 256, 0, stream>>>(
                h2, h2_is, W3p, b3, h3, h1_is, 0, modep);
            conv4_sig<<<dim3(R * 4, g), 256, 0, stream>>>(
                h3, h1_is, w4, b4, out, xp_wr, j0, ns_shift, R);
        }
    }
}

// Round 12
// 43752.878 us; speedup vs baseline: 14.9873x; 1.2376x over previous
//
#include <hip/hip_runtime.h>
#include <hip/hip_bf16.h>

// ---------------------------------------------------------------------------
// FULL FLOAT64 pipeline (rounds 4/5: state + activations must be f64).
// Round-12: r11 counters: conv2 MfmaUtil 52%, period/chunk ~8100 cyc of which
// 4096 MFMA -> ~4000 cyc barrier-staging stall; regs 252/256 -> no room for
// prefetch (r7/r8 spilled). Fix: PRODUCER/CONSUMER wave specialization:
// 512-thr blocks, waves 0-3 consume (MFMA only), waves 4-7 produce
// (global->LDS only); SIMD i hosts consumer i + producer i+4. Double-buffered
// LDS, ONE barrier per chunk. Tile 64px x 128oc (consumer = 32px x 64oc,
// acc = 64 AGPR) -> ~4x blocks for load balance. W LDS stride padded to 130
// (kills 4-way bank conflict on b-reads). Accumulation order per output
// unchanged -> bit-identical numerics vs r11.
//
//   job j = img * NSTRIP + s ; img = j >> ns_shift ; r0 = (j & (NSTRIP-1))*R
//   h0 slot: [(R+8) rows][256][8] f64 ; h1: [(R+4)][256][256] ;
//   h2: [(R+2)][256][256] ; h3 = h1 alias
//   packed weights f64: Wp[k*256+oc], k = tap*CIN+cin (tap-major)
//   xpA/xpB: [NPIX] f64 ping-pong state; d_out: [NPIX] f32
// ---------------------------------------------------------------------------

#define NPIX (4 * 256 * 256)

typedef double v4d __attribute__((ext_vector_type(4)));

// ---------------- one-wave f64-MFMA C/D-layout probe -----------------------
__global__ __launch_bounds__(64) void probe_mode(int* __restrict__ modep)
{
    int lr = threadIdx.x & 15;
    v4d p1 = {}, p2 = {};
    p1 = __builtin_amdgcn_mfma_f64_16x16x4f64((double)lr, 1.0, p1, 0, 0, 0);
    p2 = __builtin_amdgcn_mfma_f64_16x16x4f64(1.0, (double)lr, p2, 0, 0, 0);
    double v1 = __shfl(p1[0], 16);
    double v2 = __shfl(p2[0], 16);
    if (threadIdx.x == 0)
        *modep = (v1 == 16.0) ? 0 : (v1 == 4.0) ? 1 : (v2 == 16.0) ? 2 : 3;
}

// ---------------------- x (f32) -> xp (f64) init ---------------------------
__global__ __launch_bounds__(256) void xinit_kernel(
    const float* __restrict__ x, double* __restrict__ xp64)
{
    int p = blockIdx.x * 256 + threadIdx.x;
    xp64[p] = (double)x[p];
}

// ------------------- stencil features, job-sliced --------------------------
__global__ __launch_bounds__(256) void stencil_strip(
    const float* __restrict__ x, const double* __restrict__ xp,
    double* __restrict__ h0, size_t h0_is,
    int job0, int ns_shift, int R)
{
    int slot = blockIdx.y;
    int j = job0 + slot;
    int img = j >> ns_shift;
    int r0 = (j & ((1 << ns_shift) - 1)) * R;
    int pbase = img << 16;
    int y = (r0 - 4 + blockIdx.x) & 255;
    int col = threadIdx.x;
    double q[8];
    int s = 0, idx = 0;
    #pragma unroll
    for (int i = -1; i <= 1; ++i)
        #pragma unroll
        for (int jj = -1; jj <= 1; ++jj) {
            if (i == 0 && jj == 0) continue;
            int ys = (y - i) & 255, xs = (col - jj) & 255;
            double v = xp[pbase + ((ys << 8) | xs)];
            q[idx++] = v;
            s += (v > 0.5) ? 1 : 0;
        }
    double c = xp[pbase + ((y << 8) | col)];
    bool alive = c > 0.5;
    bool binnext = (s == 3) || (alive && s == 2);
    double c0 = 1.0, c1 = 0.0, c2 = 0.0, c3 = 0.0;   // count DP, ref order
    #pragma unroll
    for (int k = 0; k < 8; ++k) {
        double qq = q[k], r = 1.0 - qq;
        c3 = c3 * r + c2 * qq;
        c2 = c2 * r + c1 * qq;
        c1 = c1 * r + c0 * qq;
        c0 = c0 * r;
    }
    double xpred = c3 + c2 * c;
    double* o = h0 + slot * h0_is + ((size_t)blockIdx.x * 256 + col) * 8;
    o[0] = (double)x[pbase + ((y << 8) | col)];
    o[1] = c;
    o[2] = alive ? 1.0 : 0.0;
    o[3] = xpred;
    o[4] = binnext ? 1.0 : 0.0;
    o[5] = 0.0; o[6] = 0.0; o[7] = 0.0;
}

// ------------- f64 MFMA conv GEMM, producer/consumer waves -----------------
// Block: 512 threads = 8 waves. Tile 64 px x 128 oc.
//   consumers (waves 0-3): cw=wave, quadrant px=(cw>>1)*32, oc=(cw&1)*64;
//     each = 2x4 MFMA tiles of 16x16, acc 8 v4d = 64 AGPR.
//   producers (waves 4-7): stage A (transposed) + W into buf[ch+1&1].
// One __syncthreads per chunk; buffers strictly alternate.
template<int CIN, int TK, int KH, int KW>
__global__ __launch_bounds__(512, 2) void conv_gemm(
    const double* __restrict__ A,    // [aRows, 256, CIN] per slot
    size_t a_is,
    const double* __restrict__ Wp,   // [KH*KW*CIN, 256]
    const float* __restrict__ bias,  // [256] f32
    double* __restrict__ O,          // [oRows, 256, 256] per slot
    size_t o_is,
    int delta,
    const int* __restrict__ modep)
{
    constexpr int PW = KW / 2, PH = KH / 2;
    constexpr int CHUNKS = CIN / TK;
    constexpr int NCH = KH * KW * CHUNKS;
    __shared__ double Asmem[2][TK][66];    // [buf][k][px]  (64 + pad 2)
    __shared__ double Wsmem[2][TK][130];   // [buf][k][oc]  (128 + pad 2)

    const double* Ai = A + blockIdx.z * a_is;
    double* Oi = O + blockIdx.z * o_is;
    const int mode = *modep;               // uniform, probed this launch

    const int tid = threadIdx.x;
    const int pm0 = blockIdx.x * 64;
    const int on0 = blockIdx.y * 128;
    const int wave = tid >> 6, lane = tid & 63;
    const bool prod = wave >= 4;

    // producer mappings (ptid in [0,256))
    const int ptid = tid & 255;
    constexpr int LPP = TK / 2;            // lanes per pixel (A staging)
    constexpr int PPR = 256 / LPP;
    constexpr int ROUNDS = 64 / PPR;       // 2 for TK=16, 1 for TK=8
    const int part = ptid % LPP;
    const int pixA = ptid / LPP;
    const int wrow = ptid >> 6;
    const int wcol = (ptid & 63) << 1;

    // consumer mappings
    const int lq = lane >> 4, lr = lane & 15;
    const int wr = ((wave & 3) >> 1) * 32; // px quadrant base (0/32)
    const int wc = (wave & 1) * 64;        // oc quadrant base (0/64)

    v4d acc[2][4] = {};

    auto stage = [&](int ch, int buf) {
        int tap = ch / CHUNKS, cc = ch % CHUNKS;
        int dy = tap / KW - PH, dx = tap % KW - PW;
        int c0 = cc * TK;
        int kglob = tap * CIN + c0;
        #pragma unroll
        for (int r = 0; r < TK / 4; ++r) {
            int row = r * 4 + wrow;
            *(double2*)&Wsmem[buf][row][wcol] =
                *(const double2*)&Wp[(size_t)(kglob + row) * 256 + on0 + wcol];
        }
        #pragma unroll
        for (int r = 0; r < ROUNDS; ++r) {
            int pix = r * PPR + pixA;
            int pl = pm0 + pix;
            int yl = pl >> 8, col = pl & 255;
            int xs = (col + dx) & 255;
            int srcpx = ((yl + dy + delta) << 8) | xs;
            double2 v = *(const double2*)(Ai + (size_t)srcpx * CIN + c0 + part * 2);
            Asmem[buf][part * 2 + 0][pix] = v.x;
            Asmem[buf][part * 2 + 1][pix] = v.y;
        }
    };

    if (prod) stage(0, 0);
    __syncthreads();
    for (int ch = 0; ch < NCH; ++ch) {
        const int cur = ch & 1;
        if (prod) {
            if (ch + 1 < NCH) stage(ch + 1, cur ^ 1);
        } else {
            #pragma unroll
            for (int k0 = 0; k0 < TK / 4; ++k0) {
                const int kk = k0 * 4 + lq;
                double a[2], b[4];
                a[0] = Asmem[cur][kk][wr + lr];
                a[1] = Asmem[cur][kk][wr + 16 + lr];
                #pragma unroll
                for (int ct = 0; ct < 4; ++ct)
                    b[ct] = Wsmem[cur][kk][wc + ct * 16 + lr];
                #pragma unroll
                for (int rt = 0; rt < 2; ++rt)
                    #pragma unroll
                    for (int ct = 0; ct < 4; ++ct)
                        acc[rt][ct] = __builtin_amdgcn_mfma_f64_16x16x4f64(
                            a[rt], b[ct], acc[rt][ct], 0, 0, 0);
            }
        }
        __syncthreads();
    }

    if (!prod) {
        // epilogue: bias + relu; (row,col) per probed mode
        #pragma unroll
        for (int rt = 0; rt < 2; ++rt)
            #pragma unroll
            for (int ct = 0; ct < 4; ++ct)
                #pragma unroll
                for (int i = 0; i < 4; ++i) {
                    int hq = lq * 4 + i, hi = i * 4 + lq;
                    int rl = (mode == 0) ? hq : (mode == 1) ? hi : lr;
                    int cl = (mode <= 1) ? lr : (mode == 2) ? hq : hi;
                    int px = pm0 + wr + rt * 16 + rl;
                    int oc = on0 + wc + ct * 16 + cl;
                    Oi[(size_t)px * 256 + oc] =
                        fmax(acc[rt][ct][i] + (double)bias[oc], 0.0);
                }
    }
}

// --------------- conv4: 256->1, 3x3, + sigmoid, wave-per-pixel -------------
__global__ __launch_bounds__(256) void conv4_sig(
    const double* __restrict__ H3, size_t h3_is,
    const float* __restrict__ w4, const float* __restrict__ b4,
    float* __restrict__ out, double* __restrict__ xp_new,
    int job0, int ns_shift, int R)
{
    __shared__ double w4s[2304];     // w4[cin][kh][kw] f64
    int tid = threadIdx.x;
    for (int i = tid; i < 2304; i += 256) w4s[i] = (double)w4[i];
    __syncthreads();
    int slot = blockIdx.y;
    int j = job0 + slot;
    int img = j >> ns_shift;
    int r0 = (j & ((1 << ns_shift) - 1)) * R;
    const double* H3i = H3 + slot * h3_is;
    int pbase = img << 16;
    int lane = tid & 63, wv = tid >> 6;
    int p0 = blockIdx.x * 64 + wv * 16;
    for (int pi = 0; pi < 16; ++pi) {
        int pl = p0 + pi;
        int yl = pl >> 8, col = pl & 255;
        double acc = 0.0;
        #pragma unroll
        for (int tap = 0; tap < 9; ++tap) {
            int row = yl + tap / 3 - 1 + 1;                 // delta = 1
            int xs = (col + tap % 3 - 1) & 255;
            const double* src = H3i + (size_t)((row << 8) | xs) * 256;
            #pragma unroll
            for (int jj = 0; jj < 4; ++jj) {
                int c = lane + 64 * jj;
                acc = fma(src[c], w4s[c * 9 + tap], acc);
            }
        }
        #pragma unroll
        for (int off = 32; off; off >>= 1) acc += __shfl_xor(acc, off, 64);
        if (lane == 0) {
            double v = acc + (double)b4[0];
            double s = 1.0 / (1.0 + exp(-v));
            int p = pbase + (((r0 + yl) << 8) | col);
            out[p] = (float)s;
            xp_new[p] = s;
        }
    }
}

// ----------------------------- weight repacks (f32 -> f64) -----------------
__global__ void repack_w1(const float* __restrict__ w1, double* __restrict__ W1p) {
    int t = blockIdx.x * 256 + threadIdx.x;           // [(tap*8+cin)*256+oc]
    if (t >= 25 * 8 * 256) return;
    int oc = t & 255, cin = (t >> 8) & 7, tap = t >> 11;
    W1p[t] = (cin < 5) ? (double)w1[oc * 125 + cin * 25 + tap] : 0.0;
}
__global__ void repack_w2(const float* __restrict__ w2, double* __restrict__ W2p) {
    int t = blockIdx.x * 256 + threadIdx.x;           // [(tap*256+cin)*256+oc]
    if (t >= 9 * 256 * 256) return;
    int oc = t & 255, cin = (t >> 8) & 255, tap = t >> 16;
    W2p[t] = (double)w2[((oc << 8) | cin) * 9 + tap];
}
__global__ void repack_w3(const float* __restrict__ w3, double* __restrict__ W3p) {
    int t = blockIdx.x * 256 + threadIdx.x;           // [cin*256+oc]
    if (t >= 256 * 256) return;
    int oc = t & 255, cin = t >> 8;
    W3p[t] = (double)w3[oc * 256 + cin];
}

// ------------------------------- launcher ----------------------------------
extern "C" void kernel_launch(void* const* d_in, const int* in_sizes, int n_in,
                              void* d_out, int out_size, void* d_ws, size_t ws_size,
                              hipStream_t stream)
{
    const float* x  = (const float*)d_in[0];
    const float* w1 = (const float*)d_in[1];
    const float* b1 = (const float*)d_in[2];
    const float* w2 = (const float*)d_in[3];
    const float* b2 = (const float*)d_in[4];
    const float* w3 = (const float*)d_in[5];
    const float* b3 = (const float*)d_in[6];
    const float* w4 = (const float*)d_in[7];
    const float* b4 = (const float*)d_in[8];
    float* out = (float*)d_out;                      // f32 output

    char* ws = (char*)d_ws;
    double* W1p = (double*)(ws);                     //   409,600 B
    double* W2p = (double*)(ws + 409600ull);         // 4,718,592 B
    double* W3p = (double*)(ws + 5128192ull);        //   524,288 B
    double* xpA = (double*)(ws + 5652480ull);        // 2,097,152 B
    double* xpB = (double*)(ws + 7749632ull);        // 2,097,152 B
    int*   modep = (int*)(ws + 9846784ull);          //       256 B
    char*  bufs = ws + 9847040ull;
    const size_t base_need = 9847040ull;
    const size_t ROWD  = 524288ull;                  // 256*256 f64 row bytes
    const size_t ROWH0 = 16384ull;                   // 256*8 f64 row bytes

    // (R, G) tier ladder — preference order; ws >= ~159 MB known (r11 ran
    // (32,4)), higher tiers reduce halo waste + dispatch count if they fit.
    const int cand_r[14] = {64, 128, 256, 64, 32, 64, 16, 32, 16, 8, 8, 4, 4, 2};
    const int cand_g[14] = { 4,   2,   1,  3,  4,  2,  4,  2,  2, 4, 2, 2, 1, 1};
    int R = 2, G = 1;
    for (int ci = 0; ci < 14; ++ci) {
        int r = cand_r[ci], g = cand_g[ci];
        size_t need = base_need + (size_t)g *
            ((size_t)(r + 8) * ROWH0 + (size_t)(2 * r + 6) * ROWD);
        if (ws_size >= need) { R = r; G = g; break; }
    }
    int ns_shift = 0;
    while ((256 >> ns_shift) != R) ++ns_shift;       // R=256->0 ... R=2->7
    const int NSTRIP = 256 / R;
    const int jobs = 4 * NSTRIP;

    double* h0 = (double*)bufs;
    double* h1 = (double*)(bufs + (size_t)G * (R + 8) * ROWH0);
    double* h2 = (double*)((char*)h1 + (size_t)G * (R + 4) * ROWD);
    double* h3 = h1;                                 // alias, stride h1_is
    const size_t h0_is = (size_t)(R + 8) * 256 * 8;  // element strides
    const size_t h1_is = (size_t)(R + 4) * 256 * 256;
    const size_t h2_is = (size_t)(R + 2) * 256 * 256;

    probe_mode<<<1, 64, 0, stream>>>(modep);
    repack_w1<<<200, 256, 0, stream>>>(w1, W1p);
    repack_w2<<<2304, 256, 0, stream>>>(w2, W2p);
    repack_w3<<<256, 256, 0, stream>>>(w3, W3p);
    xinit_kernel<<<NPIX / 256, 256, 0, stream>>>(x, xpA);

    for (int it = 0; it < 5; ++it) {                 // n_it = 5 (setup constant)
        const double* xp_rd = (it & 1) ? xpB : xpA;  // ping-pong: no intra-iter
        double*       xp_wr = (it & 1) ? xpA : xpB;  // RAW hazard (round 5 bug)
        for (int j0 = 0; j0 < jobs; j0 += G) {
            int g = (jobs - j0 < G) ? (jobs - j0) : G;
            stencil_strip<<<dim3(R + 8, g), 256, 0, stream>>>(
                x, xp_rd, h0, h0_is, j0, ns_shift, R);
            conv_gemm<8, 8, 5, 5><<<dim3((R + 4) * 4, 2, g), 512, 0, stream>>>(
                h0, h0_is, W1p, b1, h1, h1_is, 2, modep);
            conv_gemm<256, 16, 3, 3><<<dim3((R + 2) * 4, 2, g), 512, 0, stream>>>(
                h1, h1_is, W2p, b2, h2, h2_is, 1, modep);
            conv_gemm<256, 16, 1, 1><<<dim3((R + 2) * 4, 2, g), 512, 0, stream>>>(
                h2, h2_is, W3p, b3, h3, h1_is, 0, modep);
            conv4_sig<<<dim3(R * 4, g), 256, 0, stream>>>(
                h3, h1_is, w4, b4, out, xp_wr, j0, ns_shift, R);
        }
    }
}

// Round 13
// 41487.042 us; speedup vs baseline: 15.8058x; 1.0546x over previous
//
#include <hip/hip_runtime.h>
#include <hip/hip_bf16.h>

// ---------------------------------------------------------------------------
// FULL FLOAT64 pipeline (rounds 4/5: state + activations must be f64).
// Round-13: r12 (producer/consumer waves) reached conv2 MfmaUtil 66%.
// Remaining idle = barrier frequency (144/block, 4096 MFMA-cyc each) +
// A-tile over-fetch (FETCH 899MB vs 104MB unique; re-read per tap x9).
// Fix: conv2-specialized kernel with dy-GROUPED staging: chunk = (dy, cc8);
// producers stage A[8ch][66px] (dx-halo included) once + 3 taps' W (24 rows);
// consumers run 3 dx x 16 = 48 MFMAs per barrier (6144 pipe-cyc/SIMD, +50%),
// NCH 96, A-traffic /2.9. Zero extra consumer registers (128-reg cliff).
// conv1/conv3 keep the r12 kernel. s_setprio 1 on consumer waves.
// Summation order conv2: dy -> cc -> dx (f64 reorder noise ~1e-13, flip-safe).
//
//   job j = img * NSTRIP + s ; img = j >> ns_shift ; r0 = (j & (NSTRIP-1))*R
//   h0 slot: [(R+8) rows][256][8] f64 ; h1: [(R+4)][256][256] ;
//   h2: [(R+2)][256][256] ; h3 = h1 alias
//   packed weights f64: Wp[k*256+oc], k = tap*CIN+cin (tap-major)
//   xpA/xpB: [NPIX] f64 ping-pong state; d_out: [NPIX] f32
// ---------------------------------------------------------------------------

#define NPIX (4 * 256 * 256)

typedef double v4d __attribute__((ext_vector_type(4)));

// ---------------- one-wave f64-MFMA C/D-layout probe -----------------------
__global__ __launch_bounds__(64) void probe_mode(int* __restrict__ modep)
{
    int lr = threadIdx.x & 15;
    v4d p1 = {}, p2 = {};
    p1 = __builtin_amdgcn_mfma_f64_16x16x4f64((double)lr, 1.0, p1, 0, 0, 0);
    p2 = __builtin_amdgcn_mfma_f64_16x16x4f64(1.0, (double)lr, p2, 0, 0, 0);
    double v1 = __shfl(p1[0], 16);
    double v2 = __shfl(p2[0], 16);
    if (threadIdx.x == 0)
        *modep = (v1 == 16.0) ? 0 : (v1 == 4.0) ? 1 : (v2 == 16.0) ? 2 : 3;
}

// ---------------------- x (f32) -> xp (f64) init ---------------------------
__global__ __launch_bounds__(256) void xinit_kernel(
    const float* __restrict__ x, double* __restrict__ xp64)
{
    int p = blockIdx.x * 256 + threadIdx.x;
    xp64[p] = (double)x[p];
}

// ------------------- stencil features, job-sliced --------------------------
__global__ __launch_bounds__(256) void stencil_strip(
    const float* __restrict__ x, const double* __restrict__ xp,
    double* __restrict__ h0, size_t h0_is,
    int job0, int ns_shift, int R)
{
    int slot = blockIdx.y;
    int j = job0 + slot;
    int img = j >> ns_shift;
    int r0 = (j & ((1 << ns_shift) - 1)) * R;
    int pbase = img << 16;
    int y = (r0 - 4 + blockIdx.x) & 255;
    int col = threadIdx.x;
    double q[8];
    int s = 0, idx = 0;
    #pragma unroll
    for (int i = -1; i <= 1; ++i)
        #pragma unroll
        for (int jj = -1; jj <= 1; ++jj) {
            if (i == 0 && jj == 0) continue;
            int ys = (y - i) & 255, xs = (col - jj) & 255;
            double v = xp[pbase + ((ys << 8) | xs)];
            q[idx++] = v;
            s += (v > 0.5) ? 1 : 0;
        }
    double c = xp[pbase + ((y << 8) | col)];
    bool alive = c > 0.5;
    bool binnext = (s == 3) || (alive && s == 2);
    double c0 = 1.0, c1 = 0.0, c2 = 0.0, c3 = 0.0;   // count DP, ref order
    #pragma unroll
    for (int k = 0; k < 8; ++k) {
        double qq = q[k], r = 1.0 - qq;
        c3 = c3 * r + c2 * qq;
        c2 = c2 * r + c1 * qq;
        c1 = c1 * r + c0 * qq;
        c0 = c0 * r;
    }
    double xpred = c3 + c2 * c;
    double* o = h0 + slot * h0_is + ((size_t)blockIdx.x * 256 + col) * 8;
    o[0] = (double)x[pbase + ((y << 8) | col)];
    o[1] = c;
    o[2] = alive ? 1.0 : 0.0;
    o[3] = xpred;
    o[4] = binnext ? 1.0 : 0.0;
    o[5] = 0.0; o[6] = 0.0; o[7] = 0.0;
}

// ------------- generic f64 MFMA conv GEMM (conv1/conv3), r12 ---------------
template<int CIN, int TK, int KH, int KW>
__global__ __launch_bounds__(512, 2) void conv_gemm(
    const double* __restrict__ A, size_t a_is,
    const double* __restrict__ Wp,
    const float* __restrict__ bias,
    double* __restrict__ O, size_t o_is,
    int delta, const int* __restrict__ modep)
{
    constexpr int PW = KW / 2, PH = KH / 2;
    constexpr int CHUNKS = CIN / TK;
    constexpr int NCH = KH * KW * CHUNKS;
    __shared__ double Asmem[2][TK][66];    // [buf][k][px]
    __shared__ double Wsmem[2][TK][130];   // [buf][k][oc]

    const double* Ai = A + blockIdx.z * a_is;
    double* Oi = O + blockIdx.z * o_is;
    const int mode = *modep;

    const int tid = threadIdx.x;
    const int pm0 = blockIdx.x * 64;
    const int on0 = blockIdx.y * 128;
    const int wave = tid >> 6, lane = tid & 63;
    const bool prod = wave >= 4;
    if (!prod) asm volatile("s_setprio 1");

    const int ptid = tid & 255;
    constexpr int LPP = TK / 2;
    constexpr int PPR = 256 / LPP;
    constexpr int ROUNDS = 64 / PPR;
    const int part = ptid % LPP;
    const int pixA = ptid / LPP;
    const int wrow = ptid >> 6;
    const int wcol = (ptid & 63) << 1;

    const int lq = lane >> 4, lr = lane & 15;
    const int wr = ((wave & 3) >> 1) * 32;
    const int wc = (wave & 1) * 64;

    v4d acc[2][4] = {};

    auto stage = [&](int ch, int buf) {
        int tap = ch / CHUNKS, cc = ch % CHUNKS;
        int dy = tap / KW - PH, dx = tap % KW - PW;
        int c0 = cc * TK;
        int kglob = tap * CIN + c0;
        #pragma unroll
        for (int r = 0; r < TK / 4; ++r) {
            int row = r * 4 + wrow;
            *(double2*)&Wsmem[buf][row][wcol] =
                *(const double2*)&Wp[(size_t)(kglob + row) * 256 + on0 + wcol];
        }
        #pragma unroll
        for (int r = 0; r < ROUNDS; ++r) {
            int pix = r * PPR + pixA;
            int pl = pm0 + pix;
            int yl = pl >> 8, col = pl & 255;
            int xs = (col + dx) & 255;
            int srcpx = ((yl + dy + delta) << 8) | xs;
            double2 v = *(const double2*)(Ai + (size_t)srcpx * CIN + c0 + part * 2);
            Asmem[buf][part * 2 + 0][pix] = v.x;
            Asmem[buf][part * 2 + 1][pix] = v.y;
        }
    };

    if (prod) stage(0, 0);
    __syncthreads();
    for (int ch = 0; ch < NCH; ++ch) {
        const int cur = ch & 1;
        if (prod) {
            if (ch + 1 < NCH) stage(ch + 1, cur ^ 1);
        } else {
            #pragma unroll
            for (int k0 = 0; k0 < TK / 4; ++k0) {
                const int kk = k0 * 4 + lq;
                double a[2], b[4];
                a[0] = Asmem[cur][kk][wr + lr];
                a[1] = Asmem[cur][kk][wr + 16 + lr];
                #pragma unroll
                for (int ct = 0; ct < 4; ++ct)
                    b[ct] = Wsmem[cur][kk][wc + ct * 16 + lr];
                #pragma unroll
                for (int rt = 0; rt < 2; ++rt)
                    #pragma unroll
                    for (int ct = 0; ct < 4; ++ct)
                        acc[rt][ct] = __builtin_amdgcn_mfma_f64_16x16x4f64(
                            a[rt], b[ct], acc[rt][ct], 0, 0, 0);
            }
        }
        __syncthreads();
    }

    if (!prod) {
        #pragma unroll
        for (int rt = 0; rt < 2; ++rt)
            #pragma unroll
            for (int ct = 0; ct < 4; ++ct)
                #pragma unroll
                for (int i = 0; i < 4; ++i) {
                    int hq = lq * 4 + i, hi = i * 4 + lq;
                    int rl = (mode == 0) ? hq : (mode == 1) ? hi : lr;
                    int cl = (mode <= 1) ? lr : (mode == 2) ? hq : hi;
                    int px = pm0 + wr + rt * 16 + rl;
                    int oc = on0 + wc + ct * 16 + cl;
                    Oi[(size_t)px * 256 + oc] =
                        fmax(acc[rt][ct][i] + (double)bias[oc], 0.0);
                }
    }
}

// ------------- conv2-specialized GEMM: 3x3, 256cin, dy-grouped -------------
// Chunk = (dy, cc8): A[8][66] staged once (dx-halo), W 24 rows (3 dx taps).
// Consumers: 3 dx x 2 k0 x 8 = 48 MFMAs per barrier. NCH = 96.
__global__ __launch_bounds__(512, 2) void conv2_gemm(
    const double* __restrict__ A, size_t a_is,    // h1 [R+4][256][256]
    const double* __restrict__ Wp,                // [2304, 256]
    const float* __restrict__ bias,
    double* __restrict__ O, size_t o_is,          // h2 [R+2][256][256]
    const int* __restrict__ modep)
{
    __shared__ double Asmem[2][8][66];     // [buf][k][px(-1..64)]
    __shared__ double Wsmem[2][24][130];   // [buf][dx*8+k][oc]

    const double* Ai = A + blockIdx.z * a_is;
    double* Oi = O + blockIdx.z * o_is;
    const int mode = *modep;

    const int tid = threadIdx.x;
    const int pm0 = blockIdx.x * 64;
    const int on0 = blockIdx.y * 128;
    const int yrow = pm0 >> 8;             // h2-local row (tile spans 1 row)
    const int col0 = pm0 & 255;
    const int wave = tid >> 6, lane = tid & 63;
    const bool prod = wave >= 4;
    if (!prod) asm volatile("s_setprio 1");

    const int ptid = tid & 255;
    const int lq = lane >> 4, lr = lane & 15;
    const int wr = ((wave & 3) >> 1) * 32;
    const int wc = (wave & 1) * 64;

    v4d acc[2][4] = {};

    auto stage = [&](int ch, int buf) {
        int dy = ch >> 5;                  // [0,3)
        int cc = ch & 31;
        int c0 = cc * 8;
        int srow = yrow + dy;              // h1 row (delta=1: yl+dy-1+1)
        // ---- A: 66 px x 8 ch = 264 double2 tasks over 256 threads ----
        {
            int px = ptid >> 2, pp = ptid & 3;
            int xs = (col0 - 1 + px) & 255;
            double2 v = *(const double2*)(
                Ai + (size_t)((srow << 8) | xs) * 256 + c0 + pp * 2);
            Asmem[buf][pp * 2 + 0][px] = v.x;
            Asmem[buf][pp * 2 + 1][px] = v.y;
            if (ptid < 8) {
                int t2 = 256 + ptid;
                int px2 = t2 >> 2, pp2 = t2 & 3;
                int xs2 = (col0 - 1 + px2) & 255;
                double2 v2 = *(const double2*)(
                    Ai + (size_t)((srow << 8) | xs2) * 256 + c0 + pp2 * 2);
                Asmem[buf][pp2 * 2 + 0][px2] = v2.x;
                Asmem[buf][pp2 * 2 + 1][px2] = v2.y;
            }
        }
        // ---- W: 24 rows x 128 oc = 1536 double2, 6 per thread ----
        #pragma unroll
        for (int i = 0; i < 6; ++i) {
            int t = ptid + 256 * i;
            int row = t >> 6;              // [0,24)
            int cp = (t & 63) << 1;
            int tap = dy * 3 + (row >> 3);
            int k = tap * 256 + c0 + (row & 7);
            *(double2*)&Wsmem[buf][row][cp] =
                *(const double2*)&Wp[(size_t)k * 256 + on0 + cp];
        }
    };

    if (prod) stage(0, 0);
    __syncthreads();
    for (int ch = 0; ch < 96; ++ch) {
        const int cur = ch & 1;
        if (prod) {
            if (ch + 1 < 96) stage(ch + 1, cur ^ 1);
        } else {
            #pragma unroll
            for (int dx = 0; dx < 3; ++dx)
                #pragma unroll
                for (int k0 = 0; k0 < 2; ++k0) {
                    const int kA = k0 * 4 + lq;
                    const int kW = dx * 8 + k0 * 4 + lq;
                    double a[2], b[4];
                    a[0] = Asmem[cur][kA][dx + wr + lr];
                    a[1] = Asmem[cur][kA][dx + wr + 16 + lr];
                    #pragma unroll
                    for (int ct = 0; ct < 4; ++ct)
                        b[ct] = Wsmem[cur][kW][wc + ct * 16 + lr];
                    #pragma unroll
                    for (int rt = 0; rt < 2; ++rt)
                        #pragma unroll
                        for (int ct = 0; ct < 4; ++ct)
                            acc[rt][ct] = __builtin_amdgcn_mfma_f64_16x16x4f64(
                                a[rt], b[ct], acc[rt][ct], 0, 0, 0);
                }
        }
        __syncthreads();
    }

    if (!prod) {
        #pragma unroll
        for (int rt = 0; rt < 2; ++rt)
            #pragma unroll
            for (int ct = 0; ct < 4; ++ct)
                #pragma unroll
                for (int i = 0; i < 4; ++i) {
                    int hq = lq * 4 + i, hi = i * 4 + lq;
                    int rl = (mode == 0) ? hq : (mode == 1) ? hi : lr;
                    int cl = (mode <= 1) ? lr : (mode == 2) ? hq : hi;
                    int px = pm0 + wr + rt * 16 + rl;
                    int oc = on0 + wc + ct * 16 + cl;
                    Oi[(size_t)px * 256 + oc] =
                        fmax(acc[rt][ct][i] + (double)bias[oc], 0.0);
                }
    }
}

// --------------- conv4: 256->1, 3x3, + sigmoid, wave-per-pixel -------------
__global__ __launch_bounds__(256) void conv4_sig(
    const double* __restrict__ H3, size_t h3_is,
    const float* __restrict__ w4, const float* __restrict__ b4,
    float* __restrict__ out, double* __restrict__ xp_new,
    int job0, int ns_shift, int R)
{
    __shared__ double w4s[2304];     // w4[cin][kh][kw] f64
    int tid = threadIdx.x;
    for (int i = tid; i < 2304; i += 256) w4s[i] = (double)w4[i];
    __syncthreads();
    int slot = blockIdx.y;
    int j = job0 + slot;
    int img = j >> ns_shift;
    int r0 = (j & ((1 << ns_shift) - 1)) * R;
    const double* H3i = H3 + slot * h3_is;
    int pbase = img << 16;
    int lane = tid & 63, wv = tid >> 6;
    int p0 = blockIdx.x * 64 + wv * 16;
    for (int pi = 0; pi < 16; ++pi) {
        int pl = p0 + pi;
        int yl = pl >> 8, col = pl & 255;
        double acc = 0.0;
        #pragma unroll
        for (int tap = 0; tap < 9; ++tap) {
            int row = yl + tap / 3 - 1 + 1;                 // delta = 1
            int xs = (col + tap % 3 - 1) & 255;
            const double* src = H3i + (size_t)((row << 8) | xs) * 256;
            #pragma unroll
            for (int jj = 0; jj < 4; ++jj) {
                int c = lane + 64 * jj;
                acc = fma(src[c], w4s[c * 9 + tap], acc);
            }
        }
        #pragma unroll
        for (int off = 32; off; off >>= 1) acc += __shfl_xor(acc, off, 64);
        if (lane == 0) {
            double v = acc + (double)b4[0];
            double s = 1.0 / (1.0 + exp(-v));
            int p = pbase + (((r0 + yl) << 8) | col);
            out[p] = (float)s;
            xp_new[p] = s;
        }
    }
}

// ----------------------------- weight repacks (f32 -> f64) -----------------
__global__ void repack_w1(const float* __restrict__ w1, double* __restrict__ W1p) {
    int t = blockIdx.x * 256 + threadIdx.x;           // [(tap*8+cin)*256+oc]
    if (t >= 25 * 8 * 256) return;
    int oc = t & 255, cin = (t >> 8) & 7, tap = t >> 11;
    W1p[t] = (cin < 5) ? (double)w1[oc * 125 + cin * 25 + tap] : 0.0;
}
__global__ void repack_w2(const float* __restrict__ w2, double* __restrict__ W2p) {
    int t = blockIdx.x * 256 + threadIdx.x;           // [(tap*256+cin)*256+oc]
    if (t >= 9 * 256 * 256) return;
    int oc = t & 255, cin = (t >> 8) & 255, tap = t >> 16;
    W2p[t] = (double)w2[((oc << 8) | cin) * 9 + tap];
}
__global__ void repack_w3(const float* __restrict__ w3, double* __restrict__ W3p) {
    int t = blockIdx.x * 256 + threadIdx.x;           // [cin*256+oc]
    if (t >= 256 * 256) return;
    int oc = t & 255, cin = t >> 8;
    W3p[t] = (double)w3[oc * 256 + cin];
}

// ------------------------------- launcher ----------------------------------
extern "C" void kernel_launch(void* const* d_in, const int* in_sizes, int n_in,
                              void* d_out, int out_size, void* d_ws, size_t ws_size,
                              hipStream_t stream)
{
    const float* x  = (const float*)d_in[0];
    const float* w1 = (const float*)d_in[1];
    const float* b1 = (const float*)d_in[2];
    const float* w2 = (const float*)d_in[3];
    const float* b2 = (const float*)d_in[4];
    const float* w3 = (const float*)d_in[5];
    const float* b3 = (const float*)d_in[6];
    const float* w4 = (const float*)d_in[7];
    const float* b4 = (const float*)d_in[8];
    float* out = (float*)d_out;                      // f32 output

    char* ws = (char*)d_ws;
    double* W1p = (double*)(ws);                     //   409,600 B
    double* W2p = (double*)(ws + 409600ull);         // 4,718,592 B
    double* W3p = (double*)(ws + 5128192ull);        //   524,288 B
    double* xpA = (double*)(ws + 5652480ull);        // 2,097,152 B
    double* xpB = (double*)(ws + 7749632ull);        // 2,097,152 B
    int*   modep = (int*)(ws + 9846784ull);          //       256 B
    char*  bufs = ws + 9847040ull;
    const size_t base_need = 9847040ull;
    const size_t ROWD  = 524288ull;                  // 256*256 f64 row bytes
    const size_t ROWH0 = 16384ull;                   // 256*8 f64 row bytes

    // (R, G) tier ladder — r12 proven; ws in [214 MB, 276 MB) -> (64,3).
    const int cand_r[14] = {64, 128, 256, 64, 32, 64, 16, 32, 16, 8, 8, 4, 4, 2};
    const int cand_g[14] = { 4,   2,   1,  3,  4,  2,  4,  2,  2, 4, 2, 2, 1, 1};
    int R = 2, G = 1;
    for (int ci = 0; ci < 14; ++ci) {
        int r = cand_r[ci], g = cand_g[ci];
        size_t need = base_need + (size_t)g *
            ((size_t)(r + 8) * ROWH0 + (size_t)(2 * r + 6) * ROWD);
        if (ws_size >= need) { R = r; G = g; break; }
    }
    int ns_shift = 0;
    while ((256 >> ns_shift) != R) ++ns_shift;       // R=256->0 ... R=2->7
    const int NSTRIP = 256 / R;
    const int jobs = 4 * NSTRIP;

    double* h0 = (double*)bufs;
    double* h1 = (double*)(bufs + (size_t)G * (R + 8) * ROWH0);
    double* h2 = (double*)((char*)h1 + (size_t)G * (R + 4) * ROWD);
    double* h3 = h1;                                 // alias, stride h1_is
    const size_t h0_is = (size_t)(R + 8) * 256 * 8;  // element strides
    const size_t h1_is = (size_t)(R + 4) * 256 * 256;
    const size_t h2_is = (size_t)(R + 2) * 256 * 256;

    probe_mode<<<1, 64, 0, stream>>>(modep);
    repack_w1<<<200, 256, 0, stream>>>(w1, W1p);
    repack_w2<<<2304, 256, 0, stream>>>(w2, W2p);
    repack_w3<<<256, 256, 0, stream>>>(w3, W3p);
    xinit_kernel<<<NPIX / 256, 256, 0, stream>>>(x, xpA);

    for (int it = 0; it < 5; ++it) {                 // n_it = 5 (setup constant)
        const double* xp_rd = (it & 1) ? xpB : xpA;  // ping-pong: no intra-iter
        double*       xp_wr = (it & 1) ? xpA : xpB;  // RAW hazard (round 5 bug)
        for (int j0 = 0; j0 < jobs; j0 += G) {
            int g = (jobs - j0 < G) ? (jobs - j0) : G;
            stencil_strip<<<dim3(R + 8, g), 256, 0, stream>>>(
                x, xp_rd, h0, h0_is, j0, ns_shift, R);
            conv_gemm<8, 8, 5, 5><<<dim3((R + 4) * 4, 2, g), 512, 0, stream>>>(
                h0, h0_is, W1p, b1, h1, h1_is, 2, modep);
            conv2_gemm<<<dim3((R + 2) * 4, 2, g), 512, 0, stream>>>(
                h1, h1_is, W2p, b2, h2, h2_is, modep);
            conv_gemm<256, 16, 1, 1><<<dim3((R + 2) * 4, 2, g), 512, 0, stream>>>(
                h2, h2_is, W3p, b3, h3, h1_is, 0, modep);
            conv4_sig<<<dim3(R * 4, g), 256, 0, stream>>>(
                h3, h1_is, w4, b4, out, xp_wr, j0, ns_shift, R);
        }
    }
}

// Round 14
// 39859.564 us; speedup vs baseline: 16.4512x; 1.0408x over previous
//
#include <hip/hip_runtime.h>
#include <hip/hip_bf16.h>

// ---------------------------------------------------------------------------
// FULL FLOAT64 pipeline (rounds 4/5: state + activations must be f64).
// Round-14: r13 counters: conv2 tail-round quantization (1584 blocks, 3.09
// residency rounds at 2 blocks/CU, 246us tile -> ~220us idle/dispatch) and
// the 128-reg combined (64 arch + 64 AGPR) occupancy cliff. Fix: retile all
// GEMMs to 64px x 64oc (4 consumers of 32x32, acc 32 AGPR, combined ~80) ->
// 3 blocks/CU via __launch_bounds__(512,6): independent per-block barriers
// overlap on each SIMD, tile time halves, tail ~60us. grid.y = 4.
// Per-output k-summation order unchanged -> bit-identical numerics.
//
//   job j = img * NSTRIP + s ; img = j >> ns_shift ; r0 = (j & (NSTRIP-1))*R
//   h0 slot: [(R+8) rows][256][8] f64 ; h1: [(R+4)][256][256] ;
//   h2: [(R+2)][256][256] ; h3 = h1 alias
//   packed weights f64: Wp[k*256+oc], k = tap*CIN+cin (tap-major)
//   xpA/xpB: [NPIX] f64 ping-pong state; d_out: [NPIX] f32
// ---------------------------------------------------------------------------

#define NPIX (4 * 256 * 256)

typedef double v4d __attribute__((ext_vector_type(4)));

// ---------------- one-wave f64-MFMA C/D-layout probe -----------------------
__global__ __launch_bounds__(64) void probe_mode(int* __restrict__ modep)
{
    int lr = threadIdx.x & 15;
    v4d p1 = {}, p2 = {};
    p1 = __builtin_amdgcn_mfma_f64_16x16x4f64((double)lr, 1.0, p1, 0, 0, 0);
    p2 = __builtin_amdgcn_mfma_f64_16x16x4f64(1.0, (double)lr, p2, 0, 0, 0);
    double v1 = __shfl(p1[0], 16);
    double v2 = __shfl(p2[0], 16);
    if (threadIdx.x == 0)
        *modep = (v1 == 16.0) ? 0 : (v1 == 4.0) ? 1 : (v2 == 16.0) ? 2 : 3;
}

// ---------------------- x (f32) -> xp (f64) init ---------------------------
__global__ __launch_bounds__(256) void xinit_kernel(
    const float* __restrict__ x, double* __restrict__ xp64)
{
    int p = blockIdx.x * 256 + threadIdx.x;
    xp64[p] = (double)x[p];
}

// ------------------- stencil features, job-sliced --------------------------
__global__ __launch_bounds__(256) void stencil_strip(
    const float* __restrict__ x, const double* __restrict__ xp,
    double* __restrict__ h0, size_t h0_is,
    int job0, int ns_shift, int R)
{
    int slot = blockIdx.y;
    int j = job0 + slot;
    int img = j >> ns_shift;
    int r0 = (j & ((1 << ns_shift) - 1)) * R;
    int pbase = img << 16;
    int y = (r0 - 4 + blockIdx.x) & 255;
    int col = threadIdx.x;
    double q[8];
    int s = 0, idx = 0;
    #pragma unroll
    for (int i = -1; i <= 1; ++i)
        #pragma unroll
        for (int jj = -1; jj <= 1; ++jj) {
            if (i == 0 && jj == 0) continue;
            int ys = (y - i) & 255, xs = (col - jj) & 255;
            double v = xp[pbase + ((ys << 8) | xs)];
            q[idx++] = v;
            s += (v > 0.5) ? 1 : 0;
        }
    double c = xp[pbase + ((y << 8) | col)];
    bool alive = c > 0.5;
    bool binnext = (s == 3) || (alive && s == 2);
    double c0 = 1.0, c1 = 0.0, c2 = 0.0, c3 = 0.0;   // count DP, ref order
    #pragma unroll
    for (int k = 0; k < 8; ++k) {
        double qq = q[k], r = 1.0 - qq;
        c3 = c3 * r + c2 * qq;
        c2 = c2 * r + c1 * qq;
        c1 = c1 * r + c0 * qq;
        c0 = c0 * r;
    }
    double xpred = c3 + c2 * c;
    double* o = h0 + slot * h0_is + ((size_t)blockIdx.x * 256 + col) * 8;
    o[0] = (double)x[pbase + ((y << 8) | col)];
    o[1] = c;
    o[2] = alive ? 1.0 : 0.0;
    o[3] = xpred;
    o[4] = binnext ? 1.0 : 0.0;
    o[5] = 0.0; o[6] = 0.0; o[7] = 0.0;
}

// ------------- generic f64 MFMA conv GEMM (conv1/conv3) --------------------
// Tile 64px x 64oc; waves 0-3 consume (32px x 32oc each, acc 4 v4d),
// waves 4-7 produce. 3 blocks/CU target.
template<int CIN, int TK, int KH, int KW>
__global__ __launch_bounds__(512, 6) void conv_gemm(
    const double* __restrict__ A, size_t a_is,
    const double* __restrict__ Wp,
    const float* __restrict__ bias,
    double* __restrict__ O, size_t o_is,
    int delta, const int* __restrict__ modep)
{
    constexpr int PW = KW / 2, PH = KH / 2;
    constexpr int CHUNKS = CIN / TK;
    constexpr int NCH = KH * KW * CHUNKS;
    __shared__ double Asmem[2][TK][66];    // [buf][k][px]
    __shared__ double Wsmem[2][TK][66];    // [buf][k][oc]

    const double* Ai = A + blockIdx.z * a_is;
    double* Oi = O + blockIdx.z * o_is;
    const int mode = *modep;

    const int tid = threadIdx.x;
    const int pm0 = blockIdx.x * 64;
    const int on0 = blockIdx.y * 64;
    const int wave = tid >> 6, lane = tid & 63;
    const bool prod = wave >= 4;
    if (!prod) asm volatile("s_setprio 1");

    const int ptid = tid & 255;
    constexpr int LPP = TK / 2;
    constexpr int PPR = 256 / LPP;
    constexpr int ROUNDS = 64 / PPR;
    const int part = ptid % LPP;
    const int pixA = ptid / LPP;
    const int wrow = ptid >> 5;            // [0,8)
    const int wcol = (ptid & 31) << 1;     // [0,64) step 2

    const int lq = lane >> 4, lr = lane & 15;
    const int wr = ((wave >> 1) & 1) * 32;
    const int wc = (wave & 1) * 32;

    v4d acc[2][2] = {};

    auto stage = [&](int ch, int buf) {
        int tap = ch / CHUNKS, cc = ch % CHUNKS;
        int dy = tap / KW - PH, dx = tap % KW - PW;
        int c0 = cc * TK;
        int kglob = tap * CIN + c0;
        #pragma unroll
        for (int r = 0; r < TK / 8; ++r) {
            int row = r * 8 + wrow;
            *(double2*)&Wsmem[buf][row][wcol] =
                *(const double2*)&Wp[(size_t)(kglob + row) * 256 + on0 + wcol];
        }
        #pragma unroll
        for (int r = 0; r < ROUNDS; ++r) {
            int pix = r * PPR + pixA;
            int pl = pm0 + pix;
            int yl = pl >> 8, col = pl & 255;
            int xs = (col + dx) & 255;
            int srcpx = ((yl + dy + delta) << 8) | xs;
            double2 v = *(const double2*)(Ai + (size_t)srcpx * CIN + c0 + part * 2);
            Asmem[buf][part * 2 + 0][pix] = v.x;
            Asmem[buf][part * 2 + 1][pix] = v.y;
        }
    };

    if (prod) stage(0, 0);
    __syncthreads();
    for (int ch = 0; ch < NCH; ++ch) {
        const int cur = ch & 1;
        if (prod) {
            if (ch + 1 < NCH) stage(ch + 1, cur ^ 1);
        } else {
            #pragma unroll
            for (int k0 = 0; k0 < TK / 4; ++k0) {
                const int kk = k0 * 4 + lq;
                double a[2], b[2];
                a[0] = Asmem[cur][kk][wr + lr];
                a[1] = Asmem[cur][kk][wr + 16 + lr];
                b[0] = Wsmem[cur][kk][wc + lr];
                b[1] = Wsmem[cur][kk][wc + 16 + lr];
                #pragma unroll
                for (int rt = 0; rt < 2; ++rt)
                    #pragma unroll
                    for (int ct = 0; ct < 2; ++ct)
                        acc[rt][ct] = __builtin_amdgcn_mfma_f64_16x16x4f64(
                            a[rt], b[ct], acc[rt][ct], 0, 0, 0);
            }
        }
        __syncthreads();
    }

    if (!prod) {
        #pragma unroll
        for (int rt = 0; rt < 2; ++rt)
            #pragma unroll
            for (int ct = 0; ct < 2; ++ct)
                #pragma unroll
                for (int i = 0; i < 4; ++i) {
                    int hq = lq * 4 + i, hi = i * 4 + lq;
                    int rl = (mode == 0) ? hq : (mode == 1) ? hi : lr;
                    int cl = (mode <= 1) ? lr : (mode == 2) ? hq : hi;
                    int px = pm0 + wr + rt * 16 + rl;
                    int oc = on0 + wc + ct * 16 + cl;
                    Oi[(size_t)px * 256 + oc] =
                        fmax(acc[rt][ct][i] + (double)bias[oc], 0.0);
                }
    }
}

// ------------- conv2-specialized GEMM: 3x3, 256cin, dy-grouped -------------
// Chunk = (dy, cc8): A[8][66] (dx-halo), W 24 rows x 64 oc. 24 MFMA/consumer
// per barrier; NCH = 96. Tile 64px x 64oc, 3 blocks/CU.
__global__ __launch_bounds__(512, 6) void conv2_gemm(
    const double* __restrict__ A, size_t a_is,    // h1 [R+4][256][256]
    const double* __restrict__ Wp,                // [2304, 256]
    const float* __restrict__ bias,
    double* __restrict__ O, size_t o_is,          // h2 [R+2][256][256]
    const int* __restrict__ modep)
{
    __shared__ double Asmem[2][8][66];     // [buf][k][px(-1..64)]
    __shared__ double Wsmem[2][24][66];    // [buf][dx*8+k][oc]

    const double* Ai = A + blockIdx.z * a_is;
    double* Oi = O + blockIdx.z * o_is;
    const int mode = *modep;

    const int tid = threadIdx.x;
    const int pm0 = blockIdx.x * 64;
    const int on0 = blockIdx.y * 64;       // grid.y = 4
    const int yrow = pm0 >> 8;             // h2-local row (tile spans 1 row)
    const int col0 = pm0 & 255;
    const int wave = tid >> 6, lane = tid & 63;
    const bool prod = wave >= 4;
    if (!prod) asm volatile("s_setprio 1");

    const int ptid = tid & 255;
    const int lq = lane >> 4, lr = lane & 15;
    const int wr = ((wave >> 1) & 1) * 32;
    const int wc = (wave & 1) * 32;

    v4d acc[2][2] = {};

    auto stage = [&](int ch, int buf) {
        int dy = ch >> 5;                  // [0,3)
        int cc = ch & 31;
        int c0 = cc * 8;
        int srow = yrow + dy;              // h1 row (delta=1: yl+dy-1+1)
        // ---- A: 66 px x 8 ch = 264 double2 tasks over 256 threads ----
        {
            int px = ptid >> 2, pp = ptid & 3;
            int xs = (col0 - 1 + px) & 255;
            double2 v = *(const double2*)(
                Ai + (size_t)((srow << 8) | xs) * 256 + c0 + pp * 2);
            Asmem[buf][pp * 2 + 0][px] = v.x;
            Asmem[buf][pp * 2 + 1][px] = v.y;
            if (ptid < 8) {
                int t2 = 256 + ptid;
                int px2 = t2 >> 2, pp2 = t2 & 3;
                int xs2 = (col0 - 1 + px2) & 255;
                double2 v2 = *(const double2*)(
                    Ai + (size_t)((srow << 8) | xs2) * 256 + c0 + pp2 * 2);
                Asmem[buf][pp2 * 2 + 0][px2] = v2.x;
                Asmem[buf][pp2 * 2 + 1][px2] = v2.y;
            }
        }
        // ---- W: 24 rows x 64 oc = 768 double2, 3 per thread ----
        #pragma unroll
        for (int i = 0; i < 3; ++i) {
            int row = i * 8 + (ptid >> 5);     // [0,24)
            int cp = (ptid & 31) << 1;
            int tap = dy * 3 + (row >> 3);
            int k = tap * 256 + c0 + (row & 7);
            *(double2*)&Wsmem[buf][row][cp] =
                *(const double2*)&Wp[(size_t)k * 256 + on0 + cp];
        }
    };

    if (prod) stage(0, 0);
    __syncthreads();
    for (int ch = 0; ch < 96; ++ch) {
        const int cur = ch & 1;
        if (prod) {
            if (ch + 1 < 96) stage(ch + 1, cur ^ 1);
        } else {
            #pragma unroll
            for (int dx = 0; dx < 3; ++dx)
                #pragma unroll
                for (int k0 = 0; k0 < 2; ++k0) {
                    const int kA = k0 * 4 + lq;
                    const int kW = dx * 8 + k0 * 4 + lq;
                    double a[2], b[2];
                    a[0] = Asmem[cur][kA][dx + wr + lr];
                    a[1] = Asmem[cur][kA][dx + wr + 16 + lr];
                    b[0] = Wsmem[cur][kW][wc + lr];
                    b[1] = Wsmem[cur][kW][wc + 16 + lr];
                    #pragma unroll
                    for (int rt = 0; rt < 2; ++rt)
                        #pragma unroll
                        for (int ct = 0; ct < 2; ++ct)
                            acc[rt][ct] = __builtin_amdgcn_mfma_f64_16x16x4f64(
                                a[rt], b[ct], acc[rt][ct], 0, 0, 0);
                }
        }
        __syncthreads();
    }

    if (!prod) {
        #pragma unroll
        for (int rt = 0; rt < 2; ++rt)
            #pragma unroll
            for (int ct = 0; ct < 2; ++ct)
                #pragma unroll
                for (int i = 0; i < 4; ++i) {
                    int hq = lq * 4 + i, hi = i * 4 + lq;
                    int rl = (mode == 0) ? hq : (mode == 1) ? hi : lr;
                    int cl = (mode <= 1) ? lr : (mode == 2) ? hq : hi;
                    int px = pm0 + wr + rt * 16 + rl;
                    int oc = on0 + wc + ct * 16 + cl;
                    Oi[(size_t)px * 256 + oc] =
                        fmax(acc[rt][ct][i] + (double)bias[oc], 0.0);
                }
    }
}

// --------------- conv4: 256->1, 3x3, + sigmoid, wave-per-pixel -------------
__global__ __launch_bounds__(256) void conv4_sig(
    const double* __restrict__ H3, size_t h3_is,
    const float* __restrict__ w4, const float* __restrict__ b4,
    float* __restrict__ out, double* __restrict__ xp_new,
    int job0, int ns_shift, int R)
{
    __shared__ double w4s[2304];     // w4[cin][kh][kw] f64
    int tid = threadIdx.x;
    for (int i = tid; i < 2304; i += 256) w4s[i] = (double)w4[i];
    __syncthreads();
    int slot = blockIdx.y;
    int j = job0 + slot;
    int img = j >> ns_shift;
    int r0 = (j & ((1 << ns_shift) - 1)) * R;
    const double* H3i = H3 + slot * h3_is;
    int pbase = img << 16;
    int lane = tid & 63, wv = tid >> 6;
    int p0 = blockIdx.x * 64 + wv * 16;
    for (int pi = 0; pi < 16; ++pi) {
        int pl = p0 + pi;
        int yl = pl >> 8, col = pl & 255;
        double acc = 0.0;
        #pragma unroll
        for (int tap = 0; tap < 9; ++tap) {
            int row = yl + tap / 3 - 1 + 1;                 // delta = 1
            int xs = (col + tap % 3 - 1) & 255;
            const double* src = H3i + (size_t)((row << 8) | xs) * 256;
            #pragma unroll
            for (int jj = 0; jj < 4; ++jj) {
                int c = lane + 64 * jj;
                acc = fma(src[c], w4s[c * 9 + tap], acc);
            }
        }
        #pragma unroll
        for (int off = 32; off; off >>= 1) acc += __shfl_xor(acc, off, 64);
        if (lane == 0) {
            double v = acc + (double)b4[0];
            double s = 1.0 / (1.0 + exp(-v));
            int p = pbase + (((r0 + yl) << 8) | col);
            out[p] = (float)s;
            xp_new[p] = s;
        }
    }
}

// ----------------------------- weight repacks (f32 -> f64) -----------------
__global__ void repack_w1(const float* __restrict__ w1, double* __restrict__ W1p) {
    int t = blockIdx.x * 256 + threadIdx.x;           // [(tap*8+cin)*256+oc]
    if (t >= 25 * 8 * 256) return;
    int oc = t & 255, cin = (t >> 8) & 7, tap = t >> 11;
    W1p[t] = (cin < 5) ? (double)w1[oc * 125 + cin * 25 + tap] : 0.0;
}
__global__ void repack_w2(const float* __restrict__ w2, double* __restrict__ W2p) {
    int t = blockIdx.x * 256 + threadIdx.x;           // [(tap*256+cin)*256+oc]
    if (t >= 9 * 256 * 256) return;
    int oc = t & 255, cin = (t >> 8) & 255, tap = t >> 16;
    W2p[t] = (double)w2[((oc << 8) | cin) * 9 + tap];
}
__global__ void repack_w3(const float* __restrict__ w3, double* __restrict__ W3p) {
    int t = blockIdx.x * 256 + threadIdx.x;           // [cin*256+oc]
    if (t >= 256 * 256) return;
    int oc = t & 255, cin = t >> 8;
    W3p[t] = (double)w3[oc * 256 + cin];
}

// ------------------------------- launcher ----------------------------------
extern "C" void kernel_launch(void* const* d_in, const int* in_sizes, int n_in,
                              void* d_out, int out_size, void* d_ws, size_t ws_size,
                              hipStream_t stream)
{
    const float* x  = (const float*)d_in[0];
    const float* w1 = (const float*)d_in[1];
    const float* b1 = (const float*)d_in[2];
    const float* w2 = (const float*)d_in[3];
    const float* b2 = (const float*)d_in[4];
    const float* w3 = (const float*)d_in[5];
    const float* b3 = (const float*)d_in[6];
    const float* w4 = (const float*)d_in[7];
    const float* b4 = (const float*)d_in[8];
    float* out = (float*)d_out;                      // f32 output

    char* ws = (char*)d_ws;
    double* W1p = (double*)(ws);                     //   409,600 B
    double* W2p = (double*)(ws + 409600ull);         // 4,718,592 B
    double* W3p = (double*)(ws + 5128192ull);        //   524,288 B
    double* xpA = (double*)(ws + 5652480ull);        // 2,097,152 B
    double* xpB = (double*)(ws + 7749632ull);        // 2,097,152 B
    int*   modep = (int*)(ws + 9846784ull);          //       256 B
    char*  bufs = ws + 9847040ull;
    const size_t base_need = 9847040ull;
    const size_t ROWD  = 524288ull;                  // 256*256 f64 row bytes
    const size_t ROWH0 = 16384ull;                   // 256*8 f64 row bytes

    // (R, G) tier ladder — r12/r13 proven; ws in [224 MB, 276 MB) -> (64,3).
    const int cand_r[14] = {64, 128, 256, 64, 32, 64, 16, 32, 16, 8, 8, 4, 4, 2};
    const int cand_g[14] = { 4,   2,   1,  3,  4,  2,  4,  2,  2, 4, 2, 2, 1, 1};
    int R = 2, G = 1;
    for (int ci = 0; ci < 14; ++ci) {
        int r = cand_r[ci], g = cand_g[ci];
        size_t need = base_need + (size_t)g *
            ((size_t)(r + 8) * ROWH0 + (size_t)(2 * r + 6) * ROWD);
        if (ws_size >= need) { R = r; G = g; break; }
    }
    int ns_shift = 0;
    while ((256 >> ns_shift) != R) ++ns_shift;       // R=256->0 ... R=2->7
    const int NSTRIP = 256 / R;
    const int jobs = 4 * NSTRIP;

    double* h0 = (double*)bufs;
    double* h1 = (double*)(bufs + (size_t)G * (R + 8) * ROWH0);
    double* h2 = (double*)((char*)h1 + (size_t)G * (R + 4) * ROWD);
    double* h3 = h1;                                 // alias, stride h1_is
    const size_t h0_is = (size_t)(R + 8) * 256 * 8;  // element strides
    const size_t h1_is = (size_t)(R + 4) * 256 * 256;
    const size_t h2_is = (size_t)(R + 2) * 256 * 256;

    probe_mode<<<1, 64, 0, stream>>>(modep);
    repack_w1<<<200, 256, 0, stream>>>(w1, W1p);
    repack_w2<<<2304, 256, 0, stream>>>(w2, W2p);
    repack_w3<<<256, 256, 0, stream>>>(w3, W3p);
    xinit_kernel<<<NPIX / 256, 256, 0, stream>>>(x, xpA);

    for (int it = 0; it < 5; ++it) {                 // n_it = 5 (setup constant)
        const double* xp_rd = (it & 1) ? xpB : xpA;  // ping-pong: no intra-iter
        double*       xp_wr = (it & 1) ? xpA : xpB;  // RAW hazard (round 5 bug)
        for (int j0 = 0; j0 < jobs; j0 += G) {
            int g = (jobs - j0 < G) ? (jobs - j0) : G;
            stencil_strip<<<dim3(R + 8, g), 256, 0, stream>>>(
                x, xp_rd, h0, h0_is, j0, ns_shift, R);
            conv_gemm<8, 8, 5, 5><<<dim3((R + 4) * 4, 4, g), 512, 0, stream>>>(
                h0, h0_is, W1p, b1, h1, h1_is, 2, modep);
            conv2_gemm<<<dim3((R + 2) * 4, 4, g), 512, 0, stream>>>(
                h1, h1_is, W2p, b2, h2, h2_is, modep);
            conv_gemm<256, 16, 1, 1><<<dim3((R + 2) * 4, 4, g), 512, 0, stream>>>(
                h2, h2_is, W3p, b3, h3, h1_is, 0, modep);
            conv4_sig<<<dim3(R * 4, g), 256, 0, stream>>>(
                h3, h1_is, w4, b4, out, xp_wr, j0, ns_shift, R);
        }
    }
}